// Round 2
// baseline (1090.109 us; speedup 1.0000x reference)
//
#include <hip/hip_runtime.h>
#include <hip/hip_bf16.h>
#include <stdint.h>

// ---------------------------------------------------------------------------
// LSTM cell, fused as one bf16 MFMA GEMM:
//   A  = [input | hidden]            : [16384][2048]  (bf16, packed in ws)
//   W  = [Wx[g] | Wh[g]] per gate g  : [4096][2048]   (bf16, packed in ws, [N][K])
//   pre[g][b][s] = sum_k A[b][k] * W[g*1024+s][k] + bias[g][s]
// Each GEMM block computes one 128x64 output tile for ALL 4 gates (A-tile
// reuse + fused elementwise epilogue, no pre[] materialization).
//
// Round 2 change: staging is REGISTER-staged (global->VGPR->ds_write_b128)
// instead of global_load_lds. Round 1 passed first validation but diverged
// after graph replays (absmax 2.78) -- consistent with a DMA-write/barrier
// race; ordinary loads/stores have compiler-guaranteed waitcnt placement.
// Prefetch of tile kt+64 is issued right after barrier 1 so HBM latency
// hides under tile kt's 64 MFMAs.
// ---------------------------------------------------------------------------

typedef short bf16x8 __attribute__((ext_vector_type(8)));
typedef float f32x4 __attribute__((ext_vector_type(4)));

#define B_ROWS 16384
#define D_K 2048

__device__ __forceinline__ unsigned short f2bf(float f) {
    unsigned u = __builtin_bit_cast(unsigned, f);
    u += 0x7FFFu + ((u >> 16) & 1u);   // round-to-nearest-even
    return (unsigned short)(u >> 16);
}

__device__ __forceinline__ float sigf(float x) { return 1.0f / (1.0f + __expf(-x)); }
__device__ __forceinline__ float tanhfast(float x) { return 2.0f / (1.0f + __expf(-2.0f * x)) - 1.0f; }

// --------------------------- pack kernels ----------------------------------

__global__ void pack_A_kernel(const float* __restrict__ x,
                              const float* __restrict__ h,
                              unsigned short* __restrict__ A) {
    const int total = B_ROWS * (D_K / 4);          // vec4 units, 512 per row
    for (int v = blockIdx.x * blockDim.x + threadIdx.x; v < total;
         v += gridDim.x * blockDim.x) {
        const int b = v >> 9;
        const int k0 = (v & 511) << 2;
        const float* src = (k0 < 1024) ? (x + (size_t)b * 1024 + k0)
                                       : (h + (size_t)b * 1024 + (k0 - 1024));
        float4 f = *(const float4*)src;
        unsigned p0 = (unsigned)f2bf(f.x) | ((unsigned)f2bf(f.y) << 16);
        unsigned p1 = (unsigned)f2bf(f.z) | ((unsigned)f2bf(f.w) << 16);
        uint2 o; o.x = p0; o.y = p1;
        *(uint2*)(A + (size_t)v * 4) = o;
    }
}

__global__ void pack_W_kernel(const float* __restrict__ Wx,
                              const float* __restrict__ Wh,
                              unsigned short* __restrict__ W) {
    const int total = 4096 * (D_K / 4);
    for (int v = blockIdx.x * blockDim.x + threadIdx.x; v < total;
         v += gridDim.x * blockDim.x) {
        const int n = v >> 9;                       // n = g*1024 + s
        const int k0 = (v & 511) << 2;
        const float* src = (k0 < 1024) ? (Wx + (size_t)n * 1024 + k0)
                                       : (Wh + (size_t)n * 1024 + (k0 - 1024));
        float4 f = *(const float4*)src;
        unsigned p0 = (unsigned)f2bf(f.x) | ((unsigned)f2bf(f.y) << 16);
        unsigned p1 = (unsigned)f2bf(f.z) | ((unsigned)f2bf(f.w) << 16);
        uint2 o; o.x = p0; o.y = p1;
        *(uint2*)(W + (size_t)v * 4) = o;
    }
}

__global__ void pack_bias_kernel(const float* __restrict__ bx,
                                 const float* __restrict__ bh,
                                 float* __restrict__ bias) {
    int i = blockIdx.x * blockDim.x + threadIdx.x;
    if (i < 4096) bias[i] = bx[i] + bh[i];
}

// --------------------------- fused GEMM ------------------------------------
// Tile: BM=128 rows (b), BN=64 cols (s) x 4 gates, BK=64.
// 256 threads = 4 waves in 2x2; each wave owns 64x32 per gate.

__global__ __launch_bounds__(256, 2) void lstm_gemm_kernel(
    const unsigned short* __restrict__ A,     // [16384][2048]
    const unsigned short* __restrict__ W,     // [4096][2048]
    const float* __restrict__ bias,           // [4096]
    const float* __restrict__ cell,           // [16384][1024]
    float* __restrict__ out) {                // new_c then h, each [16384][1024]
    __shared__ __align__(16) unsigned short sA[128 * 64];
    __shared__ __align__(16) unsigned short sW[256 * 64];   // 4 gates x [64][64]

    const int tid = threadIdx.x;
    const int wid = tid >> 6;
    const int lane = tid & 63;
    const int brow = blockIdx.y << 7;
    const int bcol = blockIdx.x << 6;
    const int wr = wid >> 1, wc = wid & 1;
    const int lr = lane & 15, lg = lane >> 4;
    const int l8 = lane >> 3;                 // row within a 1KB staging chunk
    const int lcol = (lane & 7) << 3;         // k-offset (elems) within chunk

    f32x4 acc[4][4][2];
#pragma unroll
    for (int g = 0; g < 4; ++g)
#pragma unroll
        for (int m = 0; m < 4; ++m)
#pragma unroll
            for (int n = 0; n < 2; ++n) acc[g][m][n] = (f32x4){0.f, 0.f, 0.f, 0.f};

    // staging source base addresses (k advances in the loop); per-lane.
    const unsigned short* gA[4];
#pragma unroll
    for (int i = 0; i < 4; ++i) {
        int c = wid * 4 + i;                  // chunk -> rows c*8 .. c*8+7
        gA[i] = A + (size_t)(brow + c * 8 + l8) * D_K + lcol;
    }
    const unsigned short* gW[8];
#pragma unroll
    for (int i = 0; i < 8; ++i) {
        int c = wid * 8 + i;                  // 32 chunks over 4 gate tiles
        int gg = c >> 3;
        int r = ((c & 7) << 3) + l8;
        gW[i] = W + (size_t)(gg * 1024 + bcol + r) * D_K + lcol;
    }

    // LDS destinations (linear: chunk base + lane*16 bytes)
    char* dA = (char*)sA + wid * 4 * 1024 + lane * 16;
    char* dW = (char*)sW + wid * 8 * 1024 + lane * 16;

    // prefetch first K-tile into registers
    uint4 rA[4], rW[8];
#pragma unroll
    for (int i = 0; i < 4; ++i) rA[i] = *(const uint4*)(gA[i]);
#pragma unroll
    for (int i = 0; i < 8; ++i) rW[i] = *(const uint4*)(gW[i]);

    for (int kt = 0; kt < D_K; kt += 64) {
        // write staged registers to LDS
#pragma unroll
        for (int i = 0; i < 4; ++i) *(uint4*)(dA + i * 1024) = rA[i];
#pragma unroll
        for (int i = 0; i < 8; ++i) *(uint4*)(dW + i * 1024) = rW[i];
        __syncthreads();

        // issue next-tile loads early: latency hides under the 64 MFMAs
        if (kt + 64 < D_K) {
#pragma unroll
            for (int i = 0; i < 4; ++i) rA[i] = *(const uint4*)(gA[i] + kt + 64);
#pragma unroll
            for (int i = 0; i < 8; ++i) rW[i] = *(const uint4*)(gW[i] + kt + 64);
        }

#pragma unroll
        for (int kk = 0; kk < 2; ++kk) {
            bf16x8 a[4];
#pragma unroll
            for (int m = 0; m < 4; ++m)
                a[m] = *(const bf16x8*)&sA[(wr * 64 + m * 16 + lr) * 64 + kk * 32 + lg * 8];
#pragma unroll
            for (int g = 0; g < 4; ++g) {
                const int wbase = (g * 64 + wc * 32 + lr) * 64 + kk * 32 + lg * 8;
                bf16x8 w0 = *(const bf16x8*)&sW[wbase];
                bf16x8 w1 = *(const bf16x8*)&sW[wbase + 16 * 64];
#pragma unroll
                for (int m = 0; m < 4; ++m) {
                    acc[g][m][0] = __builtin_amdgcn_mfma_f32_16x16x32_bf16(a[m], w0, acc[g][m][0], 0, 0, 0);
                    acc[g][m][1] = __builtin_amdgcn_mfma_f32_16x16x32_bf16(a[m], w1, acc[g][m][1], 0, 0, 0);
                }
            }
        }
        __syncthreads();
    }

    // fused epilogue: C/D layout col = lane&15, row = (lane>>4)*4 + reg
    float bv[4][2];
#pragma unroll
    for (int g = 0; g < 4; ++g)
#pragma unroll
        for (int n = 0; n < 2; ++n)
            bv[g][n] = bias[(g << 10) + bcol + wc * 32 + n * 16 + lr];

    float* outc = out;
    float* outh = out + (size_t)B_ROWS * 1024;
#pragma unroll
    for (int m = 0; m < 4; ++m) {
#pragma unroll
        for (int r = 0; r < 4; ++r) {
            const int b = brow + wr * 64 + m * 16 + lg * 4 + r;
            const size_t base = (size_t)b * 1024 + bcol + wc * 32;
#pragma unroll
            for (int n = 0; n < 2; ++n) {
                const int so = n * 16 + lr;
                float pf = acc[0][m][n][r] + bv[0][n];
                float pi = acc[1][m][n][r] + bv[1][n];
                float pc = acc[2][m][n][r] + bv[2][n];
                float po = acc[3][m][n][r] + bv[3][n];
                float cl = cell[base + so];
                float nc = cl * sigf(pf) + sigf(pi) * tanhfast(pc);
                outc[base + so] = nc;
                outh[base + so] = tanhfast(nc) * sigf(po);
            }
        }
    }
}

// ------------------- fp32 fallback (ws too small; slow but correct) --------

__global__ void lstm_naive_kernel(const float* __restrict__ x,
                                  const float* __restrict__ cell,
                                  const float* __restrict__ h,
                                  const float* __restrict__ Wx,
                                  const float* __restrict__ bx,
                                  const float* __restrict__ Wh,
                                  const float* __restrict__ bh,
                                  float* __restrict__ out) {
    int idx = blockIdx.x * blockDim.x + threadIdx.x;
    if (idx >= B_ROWS * 1024) return;
    int b = idx >> 10, s = idx & 1023;
    const float* xr = x + (size_t)b * 1024;
    const float* hr = h + (size_t)b * 1024;
    float pre[4];
#pragma unroll
    for (int g = 0; g < 4; ++g) {
        float acc = bx[(g << 10) + s] + bh[(g << 10) + s];
        const float* wx = Wx + ((size_t)(g << 10) + s) * 1024;
        const float* wh = Wh + ((size_t)(g << 10) + s) * 1024;
        for (int k = 0; k < 1024; ++k) acc += xr[k] * wx[k] + hr[k] * wh[k];
        pre[g] = acc;
    }
    float nc = cell[idx] * sigf(pre[0]) + sigf(pre[1]) * tanhfast(pre[2]);
    out[idx] = nc;
    out[(size_t)B_ROWS * 1024 + idx] = tanhfast(nc) * sigf(pre[3]);
}

// ---------------------------------------------------------------------------

extern "C" void kernel_launch(void* const* d_in, const int* in_sizes, int n_in,
                              void* d_out, int out_size, void* d_ws, size_t ws_size,
                              hipStream_t stream) {
    const float* x    = (const float*)d_in[0];
    const float* cell = (const float*)d_in[1];
    const float* hid  = (const float*)d_in[2];
    const float* Wx   = (const float*)d_in[3];
    const float* bx   = (const float*)d_in[4];
    const float* Wh   = (const float*)d_in[5];
    const float* bh   = (const float*)d_in[6];
    float* out = (float*)d_out;

    const size_t szA = (size_t)B_ROWS * D_K * 2;    // 64 MB
    const size_t szW = (size_t)4096 * D_K * 2;      // 16 MB
    const size_t szB = 4096 * 4;
    if (ws_size < szA + szW + szB) {
        lstm_naive_kernel<<<(B_ROWS * 1024) / 256, 256, 0, stream>>>(
            x, cell, hid, Wx, bx, Wh, bh, out);
        return;
    }

    unsigned short* Ab = (unsigned short*)d_ws;
    unsigned short* Wb = (unsigned short*)((char*)d_ws + szA);
    float* bias = (float*)((char*)d_ws + szA + szW);

    pack_A_kernel<<<8192, 256, 0, stream>>>(x, hid, Ab);
    pack_W_kernel<<<2048, 256, 0, stream>>>(Wx, Wh, Wb);
    pack_bias_kernel<<<16, 256, 0, stream>>>(bx, bh, bias);

    dim3 grid(16, 128);   // 16 col-tiles (64 wide) x 128 row-tiles (128 tall)
    lstm_gemm_kernel<<<grid, 256, 0, stream>>>(Ab, Wb, bias, cell, out);
}